// Round 1
// baseline (131.513 us; speedup 1.0000x reference)
//
#include <hip/hip_runtime.h>
#include <math.h>

#define HIDDEN 200
#define ROWS_PER_BLOCK 4

// ---------------------------------------------------------------------------
// Kernel 1: precompute per-(entity|relation|time) partial-logit tables.
//   A_g[e,:] = ent_emb[e,:] @ g_w[  0:200,:]
//   B_g[r,:] = rel_emb[r,:] @ g_w[200:400,:]
//   T_g[:]   = tim_emb[0,:] @ g_w[400:600,:] + g_b      (bias folded here)
// and the same with c_w/c_b.  gridDim.y = 6 segments.
// ---------------------------------------------------------------------------
__global__ __launch_bounds__(256) void precompute_kernel(
    const float* __restrict__ ent, const float* __restrict__ rel,
    const float* __restrict__ tim,
    const float* __restrict__ g_w, const float* __restrict__ g_b,
    const float* __restrict__ c_w, const float* __restrict__ c_b,
    float* __restrict__ Ag, float* __restrict__ Bg, float* __restrict__ Tg,
    float* __restrict__ Ac, float* __restrict__ Bc, float* __restrict__ Tc) {
  const float* in;
  const float* w;
  const float* bias = nullptr;
  float* out;
  int nrows, k0;
  switch (blockIdx.y) {
    case 0:  in = ent; w = g_w; out = Ag; nrows = 1000; k0 = 0;   break;
    case 1:  in = rel; w = g_w; out = Bg; nrows = 100;  k0 = 200; break;
    case 2:  in = tim; w = g_w; out = Tg; nrows = 1;    k0 = 400; bias = g_b; break;
    case 3:  in = ent; w = c_w; out = Ac; nrows = 1000; k0 = 0;   break;
    case 4:  in = rel; w = c_w; out = Bc; nrows = 100;  k0 = 200; break;
    default: in = tim; w = c_w; out = Tc; nrows = 1;    k0 = 400; bias = c_b; break;
  }
  int row0 = blockIdx.x * ROWS_PER_BLOCK;
  if (row0 >= nrows) return;
  int nr = nrows - row0;
  if (nr > ROWS_PER_BLOCK) nr = ROWS_PER_BLOCK;

  __shared__ float a_lds[ROWS_PER_BLOCK][HIDDEN];
  int c = threadIdx.x;
  if (c < HIDDEN) {
    for (int j = 0; j < nr; ++j) a_lds[j][c] = in[(row0 + j) * HIDDEN + c];
  }
  __syncthreads();
  if (c >= HIDDEN) return;

  float acc[ROWS_PER_BLOCK] = {0.f, 0.f, 0.f, 0.f};
  const float* wp = w + k0 * HIDDEN + c;
  #pragma unroll 4
  for (int k = 0; k < HIDDEN; ++k) {
    float wv = wp[k * HIDDEN];
    #pragma unroll
    for (int j = 0; j < ROWS_PER_BLOCK; ++j) acc[j] += a_lds[j][k] * wv;
  }
  float bv = bias ? bias[c] : 0.f;
  for (int j = 0; j < nr; ++j) out[(row0 + j) * HIDDEN + c] = acc[j] + bv;
}

// ---------------------------------------------------------------------------
// Kernel 2: one 64-lane wave per query. Lanes 0..49 each hold 4 contiguous
// logits (float4). mask cancels under softmax shift-invariance -> never
// touch the history arrays.  out = log(0.5*softmax(lg) + 0.5*softmax(lc)).
// ---------------------------------------------------------------------------
__global__ __launch_bounds__(256) void query_kernel(
    const float* __restrict__ Ag, const float* __restrict__ Bg,
    const float* __restrict__ Tg, const float* __restrict__ Ac,
    const float* __restrict__ Bc, const float* __restrict__ Tc,
    const int* __restrict__ sub, const int* __restrict__ rel,
    float* __restrict__ out, int N) {
  int gtid = blockIdx.x * blockDim.x + threadIdx.x;
  int q = gtid >> 6;
  int lane = threadIdx.x & 63;
  if (q >= N) return;

  int s = sub[q];
  int r = rel[q];
  bool act = lane < (HIDDEN / 4);  // 50 active lanes

  float lg[4], lc[4];
  float mg = -INFINITY, mc = -INFINITY;
  if (act) {
    float4 a = ((const float4*)(Ag + s * HIDDEN))[lane];
    float4 b = ((const float4*)(Bg + r * HIDDEN))[lane];
    float4 t = ((const float4*)Tg)[lane];
    lg[0] = a.x + b.x + t.x;
    lg[1] = a.y + b.y + t.y;
    lg[2] = a.z + b.z + t.z;
    lg[3] = a.w + b.w + t.w;
    a = ((const float4*)(Ac + s * HIDDEN))[lane];
    b = ((const float4*)(Bc + r * HIDDEN))[lane];
    t = ((const float4*)Tc)[lane];
    lc[0] = tanhf(a.x + b.x + t.x);
    lc[1] = tanhf(a.y + b.y + t.y);
    lc[2] = tanhf(a.z + b.z + t.z);
    lc[3] = tanhf(a.w + b.w + t.w);
    #pragma unroll
    for (int j = 0; j < 4; ++j) {
      mg = fmaxf(mg, lg[j]);
      mc = fmaxf(mc, lc[j]);
    }
  }
  #pragma unroll
  for (int m = 32; m > 0; m >>= 1) {
    mg = fmaxf(mg, __shfl_xor(mg, m));
    mc = fmaxf(mc, __shfl_xor(mc, m));
  }

  float eg[4], ec[4];
  float sg = 0.f, sc = 0.f;
  if (act) {
    #pragma unroll
    for (int j = 0; j < 4; ++j) {
      eg[j] = expf(lg[j] - mg);
      ec[j] = expf(lc[j] - mc);
      sg += eg[j];
      sc += ec[j];
    }
  }
  #pragma unroll
  for (int m = 32; m > 0; m >>= 1) {
    sg += __shfl_xor(sg, m);
    sc += __shfl_xor(sc, m);
  }

  if (act) {
    float ig = 0.5f / sg;
    float ic = 0.5f / sc;
    float4 o;
    o.x = logf(eg[0] * ig + ec[0] * ic);
    o.y = logf(eg[1] * ig + ec[1] * ic);
    o.z = logf(eg[2] * ig + ec[2] * ic);
    o.w = logf(eg[3] * ig + ec[3] * ic);
    ((float4*)(out + q * HIDDEN))[lane] = o;
  }
}

// ---------------------------------------------------------------------------
extern "C" void kernel_launch(void* const* d_in, const int* in_sizes, int n_in,
                              void* d_out, int out_size, void* d_ws, size_t ws_size,
                              hipStream_t stream) {
  const float* ent  = (const float*)d_in[0];
  const float* relE = (const float*)d_in[1];
  const float* tim  = (const float*)d_in[2];
  const float* g_w  = (const float*)d_in[3];
  const float* g_b  = (const float*)d_in[4];
  const float* c_w  = (const float*)d_in[5];
  const float* c_b  = (const float*)d_in[6];
  // d_in[7..9] (history) are mathematically dead: the copy-mask is a per-row
  // constant added to every softmax logit, which cancels exactly.
  const int* sub = (const int*)d_in[10];
  const int* rel = (const int*)d_in[11];
  float* out = (float*)d_out;
  int N = in_sizes[10];

  float* ws = (float*)d_ws;
  float* Ag = ws;                 // 1000*200
  float* Ac = ws + 200000;        // 1000*200
  float* Bg = ws + 400000;        // 100*200
  float* Bc = ws + 420000;        // 100*200
  float* Tg = ws + 440000;        // 200
  float* Tc = ws + 440200;        // 200

  dim3 grid1((1000 + ROWS_PER_BLOCK - 1) / ROWS_PER_BLOCK, 6);
  precompute_kernel<<<grid1, 256, 0, stream>>>(ent, relE, tim, g_w, g_b, c_w,
                                               c_b, Ag, Bg, Tg, Ac, Bc, Tc);

  long long threads = (long long)N * 64;
  int blocks = (int)((threads + 255) / 256);
  query_kernel<<<blocks, 256, 0, stream>>>(Ag, Bg, Tg, Ac, Bc, Tc, sub, rel,
                                           out, N);
}

// Round 2
// 125.794 us; speedup vs baseline: 1.0455x; 1.0455x over previous
//
#include <hip/hip_runtime.h>
#include <math.h>

#define HIDDEN 200
#define ROWS_PER_BLOCK 4

#define LOG2E 1.4426950408889634f
#define LN2   0.6931471805599453f

__device__ __forceinline__ float fast_exp(float x) {
  return __builtin_amdgcn_exp2f(x * LOG2E);
}
__device__ __forceinline__ float fast_log(float x) {
  return __builtin_amdgcn_logf(x) * LN2;
}
__device__ __forceinline__ float fast_tanh(float x) {
  // tanh(x) = (e^{2x}-1)/(e^{2x}+1); clamp so e2 stays finite (inputs ~0.06)
  x = fminf(fmaxf(x, -10.f), 10.f);
  float e2 = __builtin_amdgcn_exp2f(x * (2.f * LOG2E));
  return (e2 - 1.f) * __builtin_amdgcn_rcpf(e2 + 1.f);
}

// ---------------------------------------------------------------------------
// Kernel 1: precompute per-(entity|relation|time) partial-logit tables.
//   A_g[e,:] = ent_emb[e,:] @ g_w[  0:200,:]
//   B_g[r,:] = rel_emb[r,:] @ g_w[200:400,:]
//   T_g[:]   = tim_emb[0,:] @ g_w[400:600,:] + g_b      (bias folded here)
// and the same with c_w/c_b.  gridDim.y = 6 segments.
// ---------------------------------------------------------------------------
__global__ __launch_bounds__(256) void precompute_kernel(
    const float* __restrict__ ent, const float* __restrict__ rel,
    const float* __restrict__ tim,
    const float* __restrict__ g_w, const float* __restrict__ g_b,
    const float* __restrict__ c_w, const float* __restrict__ c_b,
    float* __restrict__ Ag, float* __restrict__ Bg, float* __restrict__ Tg,
    float* __restrict__ Ac, float* __restrict__ Bc, float* __restrict__ Tc) {
  const float* in;
  const float* w;
  const float* bias = nullptr;
  float* out;
  int nrows, k0;
  switch (blockIdx.y) {
    case 0:  in = ent; w = g_w; out = Ag; nrows = 1000; k0 = 0;   break;
    case 1:  in = rel; w = g_w; out = Bg; nrows = 100;  k0 = 200; break;
    case 2:  in = tim; w = g_w; out = Tg; nrows = 1;    k0 = 400; bias = g_b; break;
    case 3:  in = ent; w = c_w; out = Ac; nrows = 1000; k0 = 0;   break;
    case 4:  in = rel; w = c_w; out = Bc; nrows = 100;  k0 = 200; break;
    default: in = tim; w = c_w; out = Tc; nrows = 1;    k0 = 400; bias = c_b; break;
  }
  int row0 = blockIdx.x * ROWS_PER_BLOCK;
  if (row0 >= nrows) return;
  int nr = nrows - row0;
  if (nr > ROWS_PER_BLOCK) nr = ROWS_PER_BLOCK;

  __shared__ float a_lds[ROWS_PER_BLOCK][HIDDEN];
  int c = threadIdx.x;
  if (c < HIDDEN) {
    for (int j = 0; j < nr; ++j) a_lds[j][c] = in[(row0 + j) * HIDDEN + c];
  }
  __syncthreads();
  if (c >= HIDDEN) return;

  float acc[ROWS_PER_BLOCK] = {0.f, 0.f, 0.f, 0.f};
  const float* wp = w + k0 * HIDDEN + c;
  #pragma unroll 4
  for (int k = 0; k < HIDDEN; ++k) {
    float wv = wp[k * HIDDEN];
    #pragma unroll
    for (int j = 0; j < ROWS_PER_BLOCK; ++j) acc[j] += a_lds[j][k] * wv;
  }
  float bv = bias ? bias[c] : 0.f;
  for (int j = 0; j < nr; ++j) out[(row0 + j) * HIDDEN + c] = acc[j] + bv;
}

// ---------------------------------------------------------------------------
// Kernel 2: one 64-lane wave per query. Lanes 0..49 each hold 4 contiguous
// logits (float4). The copy-mode history mask is a per-row constant added to
// every logit -> cancels exactly under softmax shift-invariance, so history
// arrays are never read.  out = log(0.5*softmax(lg) + 0.5*softmax(tanh-lc)).
// All transcendentals are single-instruction HW ops (v_exp/v_log/v_rcp).
// ---------------------------------------------------------------------------
__global__ __launch_bounds__(256) void query_kernel(
    const float* __restrict__ Ag, const float* __restrict__ Bg,
    const float* __restrict__ Tg, const float* __restrict__ Ac,
    const float* __restrict__ Bc, const float* __restrict__ Tc,
    const int* __restrict__ sub, const int* __restrict__ rel,
    float* __restrict__ out, int N) {
  int gtid = blockIdx.x * blockDim.x + threadIdx.x;
  int q = gtid >> 6;
  int lane = threadIdx.x & 63;
  if (q >= N) return;

  int s = sub[q];
  int r = rel[q];
  bool act = lane < (HIDDEN / 4);  // 50 active lanes

  float lg[4], lc[4];
  float mg = -INFINITY, mc = -INFINITY;
  if (act) {
    float4 a = ((const float4*)(Ag + s * HIDDEN))[lane];
    float4 b = ((const float4*)(Bg + r * HIDDEN))[lane];
    float4 t = ((const float4*)Tg)[lane];
    lg[0] = a.x + b.x + t.x;
    lg[1] = a.y + b.y + t.y;
    lg[2] = a.z + b.z + t.z;
    lg[3] = a.w + b.w + t.w;
    a = ((const float4*)(Ac + s * HIDDEN))[lane];
    b = ((const float4*)(Bc + r * HIDDEN))[lane];
    t = ((const float4*)Tc)[lane];
    lc[0] = fast_tanh(a.x + b.x + t.x);
    lc[1] = fast_tanh(a.y + b.y + t.y);
    lc[2] = fast_tanh(a.z + b.z + t.z);
    lc[3] = fast_tanh(a.w + b.w + t.w);
    #pragma unroll
    for (int j = 0; j < 4; ++j) {
      mg = fmaxf(mg, lg[j]);
      mc = fmaxf(mc, lc[j]);
    }
  }
  #pragma unroll
  for (int m = 32; m > 0; m >>= 1) {
    mg = fmaxf(mg, __shfl_xor(mg, m));
    mc = fmaxf(mc, __shfl_xor(mc, m));
  }

  float eg[4], ec[4];
  float sg = 0.f, sc = 0.f;
  if (act) {
    #pragma unroll
    for (int j = 0; j < 4; ++j) {
      eg[j] = fast_exp(lg[j] - mg);
      ec[j] = fast_exp(lc[j] - mc);
      sg += eg[j];
      sc += ec[j];
    }
  }
  #pragma unroll
  for (int m = 32; m > 0; m >>= 1) {
    sg += __shfl_xor(sg, m);
    sc += __shfl_xor(sc, m);
  }

  if (act) {
    float ig = 0.5f * __builtin_amdgcn_rcpf(sg);
    float ic = 0.5f * __builtin_amdgcn_rcpf(sc);
    float4 o;
    o.x = fast_log(eg[0] * ig + ec[0] * ic);
    o.y = fast_log(eg[1] * ig + ec[1] * ic);
    o.z = fast_log(eg[2] * ig + ec[2] * ic);
    o.w = fast_log(eg[3] * ig + ec[3] * ic);
    ((float4*)(out + q * HIDDEN))[lane] = o;
  }
}

// ---------------------------------------------------------------------------
extern "C" void kernel_launch(void* const* d_in, const int* in_sizes, int n_in,
                              void* d_out, int out_size, void* d_ws, size_t ws_size,
                              hipStream_t stream) {
  const float* ent  = (const float*)d_in[0];
  const float* relE = (const float*)d_in[1];
  const float* tim  = (const float*)d_in[2];
  const float* g_w  = (const float*)d_in[3];
  const float* g_b  = (const float*)d_in[4];
  const float* c_w  = (const float*)d_in[5];
  const float* c_b  = (const float*)d_in[6];
  // d_in[7..9] (history) are mathematically dead: the copy-mask is a per-row
  // constant added to every softmax logit, which cancels exactly.
  const int* sub = (const int*)d_in[10];
  const int* rel = (const int*)d_in[11];
  float* out = (float*)d_out;
  int N = in_sizes[10];

  float* ws = (float*)d_ws;
  float* Ag = ws;                 // 1000*200
  float* Ac = ws + 200000;        // 1000*200
  float* Bg = ws + 400000;        // 100*200
  float* Bc = ws + 420000;        // 100*200
  float* Tg = ws + 440000;        // 200
  float* Tc = ws + 440200;        // 200

  dim3 grid1((1000 + ROWS_PER_BLOCK - 1) / ROWS_PER_BLOCK, 6);
  precompute_kernel<<<grid1, 256, 0, stream>>>(ent, relE, tim, g_w, g_b, c_w,
                                               c_b, Ag, Bg, Tg, Ac, Bc, Tc);

  long long threads = (long long)N * 64;
  int blocks = (int)((threads + 255) / 256);
  query_kernel<<<blocks, 256, 0, stream>>>(Ag, Bg, Tg, Ac, Bc, Tc, sub, rel,
                                           out, N);
}